// Round 1
// baseline (56.780 us; speedup 1.0000x reference)
//
#include <hip/hip_runtime.h>

#define SEQ_LEN 131072
#define D_MODEL 512
#define M_SIZE  1000
#define BETA    0.5f

// ---------------------------------------------------------------------------
// Transpose W_m [D_MODEL][M] -> W_mT [M][D_MODEL] so the per-row gather in the
// main kernel becomes contiguous float4 loads. LDS-tiled to keep both global
// read and write coalesced (2 MB total; runs once, ~2 us).
// ---------------------------------------------------------------------------
__global__ void transpose_wm_kernel(const float* __restrict__ W_m,
                                    float* __restrict__ W_mT) {
    __shared__ float tile[32][33];  // +1 pad: no LDS bank conflicts
    const int bx = blockIdx.x;      // tile along M (cols of W_m)
    const int by = blockIdx.y;      // tile along D (rows of W_m)
    const int tx = threadIdx.x;     // 0..31
    const int ty = threadIdx.y;     // 0..7

    const int m = bx * 32 + tx;
    const int d0 = by * 32;
    // load: coalesced along M
    for (int i = ty; i < 32; i += 8) {
        const int d = d0 + i;
        tile[i][tx] = (m < M_SIZE) ? W_m[(long)d * M_SIZE + m] : 0.0f;
    }
    __syncthreads();
    // store: coalesced along D
    const int m0 = bx * 32;
    for (int i = ty; i < 32; i += 8) {
        const int mm = m0 + i;
        if (mm < M_SIZE) W_mT[(long)mm * D_MODEL + d0 + tx] = tile[tx][i];
    }
}

// ---------------------------------------------------------------------------
// Main kernel: one float4 (4 consecutive d) per thread-iteration.
// 128 float4 per row; flat grid-stride over S*128 float4s.
// ---------------------------------------------------------------------------
__global__ void embed_kernel(const float* __restrict__ t,
                             const int* __restrict__ marker,
                             const float* __restrict__ W_mT,
                             const float* __restrict__ W_t,
                             const float* __restrict__ b_t,
                             float* __restrict__ out) {
    const long total4 = (long)SEQ_LEN * (D_MODEL / 4);  // 16,777,216
    const long stride = (long)gridDim.x * blockDim.x;
    for (long idx = (long)blockIdx.x * blockDim.x + threadIdx.x;
         idx < total4; idx += stride) {
        const int s = (int)(idx >> 7);        // row
        const int c = (int)(idx & 127);       // float4 index within row
        const float tv = t[s];
        float4 o;
        if (tv < 0.0f) {
            o.x = 0.0f; o.y = 0.0f; o.z = 0.0f; o.w = 0.0f;
        } else {
            const int m = marker[s];
            const float4 em = reinterpret_cast<const float4*>(W_mT + (long)m * D_MODEL)[c];
            const float4 w  = reinterpret_cast<const float4*>(W_t)[c];
            const float4 b  = reinterpret_cast<const float4*>(b_t)[c];
            o.x = BETA * em.x + (1.0f - BETA) * fmaf(tv, w.x, b.x);
            o.y = BETA * em.y + (1.0f - BETA) * fmaf(tv, w.y, b.y);
            o.z = BETA * em.z + (1.0f - BETA) * fmaf(tv, w.z, b.z);
            o.w = BETA * em.w + (1.0f - BETA) * fmaf(tv, w.w, b.w);
        }
        reinterpret_cast<float4*>(out)[idx] = o;
    }
}

// ---------------------------------------------------------------------------
// Fallback (no workspace for the transpose): gather columns of W_m directly.
// Scalar loads, L2-resident (W_m = 2 MB) — correct, slower.
// ---------------------------------------------------------------------------
__global__ void embed_kernel_notrans(const float* __restrict__ t,
                                     const int* __restrict__ marker,
                                     const float* __restrict__ W_m,
                                     const float* __restrict__ W_t,
                                     const float* __restrict__ b_t,
                                     float* __restrict__ out) {
    const long total4 = (long)SEQ_LEN * (D_MODEL / 4);
    const long stride = (long)gridDim.x * blockDim.x;
    for (long idx = (long)blockIdx.x * blockDim.x + threadIdx.x;
         idx < total4; idx += stride) {
        const int s = (int)(idx >> 7);
        const int c = (int)(idx & 127);
        const float tv = t[s];
        float4 o;
        if (tv < 0.0f) {
            o.x = 0.0f; o.y = 0.0f; o.z = 0.0f; o.w = 0.0f;
        } else {
            const int m = marker[s];
            const int d = c * 4;
            const float4 w = reinterpret_cast<const float4*>(W_t)[c];
            const float4 b = reinterpret_cast<const float4*>(b_t)[c];
            o.x = BETA * W_m[(long)(d + 0) * M_SIZE + m] + (1.0f - BETA) * fmaf(tv, w.x, b.x);
            o.y = BETA * W_m[(long)(d + 1) * M_SIZE + m] + (1.0f - BETA) * fmaf(tv, w.y, b.y);
            o.z = BETA * W_m[(long)(d + 2) * M_SIZE + m] + (1.0f - BETA) * fmaf(tv, w.z, b.z);
            o.w = BETA * W_m[(long)(d + 3) * M_SIZE + m] + (1.0f - BETA) * fmaf(tv, w.w, b.w);
        }
        reinterpret_cast<float4*>(out)[idx] = o;
    }
}

extern "C" void kernel_launch(void* const* d_in, const int* in_sizes, int n_in,
                              void* d_out, int out_size, void* d_ws, size_t ws_size,
                              hipStream_t stream) {
    const float* t      = (const float*)d_in[0];
    const int*   marker = (const int*)d_in[1];
    const float* W_m    = (const float*)d_in[2];
    const float* W_t    = (const float*)d_in[3];
    const float* b_t    = (const float*)d_in[4];
    float* out = (float*)d_out;

    const size_t wmT_bytes = (size_t)M_SIZE * D_MODEL * sizeof(float);  // 2 MB

    // Memory-bound grid: 2048 blocks x 256 threads, grid-stride (G11).
    const int blocks = 2048;
    const int threads = 256;

    if (ws_size >= wmT_bytes) {
        float* W_mT = (float*)d_ws;
        dim3 tgrid((M_SIZE + 31) / 32, D_MODEL / 32);  // 32 x 16
        dim3 tblock(32, 8);
        transpose_wm_kernel<<<tgrid, tblock, 0, stream>>>(W_m, W_mT);
        embed_kernel<<<blocks, threads, 0, stream>>>(t, marker, W_mT, W_t, b_t, out);
    } else {
        embed_kernel_notrans<<<blocks, threads, 0, stream>>>(t, marker, W_m, W_t, b_t, out);
    }
}